// Round 7
// baseline (830.830 us; speedup 1.0000x reference)
//
#include <hip/hip_runtime.h>
#include <math.h>

#define D_MODEL 768
#define D_INNER 1536
#define B_SZ 4
#define T_SZ 512
#define ROWS (B_SZ*T_SZ)   // 2048
#define XP_N 80
#define CH 16              // scan chunks
#define CT 32              // T per chunk
#define XS 8               // x_proj split-K factor
#define XKC (D_INNER/XS)   // 192
#define OS 4               // out_proj split-K factor
#define OKC (D_INNER/OS)   // 384
#define MN_OUT (ROWS*768)  // 1572864

typedef __attribute__((ext_vector_type(8))) short bf16x8;
typedef __attribute__((ext_vector_type(4))) float f32x4;

// async global->LDS, 16B per lane, lane-contiguous LDS destination
#define GLL(g, l) __builtin_amdgcn_global_load_lds( \
    (const __attribute__((address_space(1))) void*)(g), \
    (__attribute__((address_space(3))) void*)(l), 16, 0, 0)

__device__ __forceinline__ float sigmoidf_(float x){ return 1.0f/(1.0f+__expf(-x)); }
__device__ __forceinline__ float siluf_(float x){ return x*sigmoidf_(x); }
__device__ __forceinline__ unsigned short f2bf(float f){
  unsigned u = __builtin_bit_cast(unsigned, f);
  u = (u + 0x7FFFu + ((u >> 16) & 1u)) >> 16;   // RNE
  return (unsigned short)u;
}
__device__ __forceinline__ ushort4 cvt4(float4 v){
  ushort4 r; r.x=f2bf(v.x); r.y=f2bf(v.y); r.z=f2bf(v.z); r.w=f2bf(v.w); return r;
}

// ---------------- one-time cast of ALL layer weights to bf16 (w/ padding) ----------------
// seg0 in_proj 4x3072x768 | seg1 out_proj 4x768x1536 | seg2 inp_w 768x256
// seg3 x_proj padded (l,128,1536) rows>=80 zero | seg4 dt_proj padded (l,1536,64) cols>=48 zero
#define CA_N0 9437184LL
#define CA_N1 4718592LL
#define CA_N2 196608LL
#define CA_N3 786432LL
#define CA_N4 393216LL
__global__ __launch_bounds__(256) void cast_all(
    const float* __restrict__ ipw, unsigned short* __restrict__ wbi,
    const float* __restrict__ opw, unsigned short* __restrict__ wbo,
    const float* __restrict__ inpw, unsigned short* __restrict__ inpwb,
    const float* __restrict__ xpw, unsigned short* __restrict__ xpwb,
    const float* __restrict__ dtw, unsigned short* __restrict__ dtwb)
{
  long long i4 = ((long long)blockIdx.x*256 + threadIdx.x)*4;
  if (i4 < CA_N0){ *(ushort4*)(wbi + i4) = cvt4(*(const float4*)(ipw + i4)); return; }
  i4 -= CA_N0;
  if (i4 < CA_N1){ *(ushort4*)(wbo + i4) = cvt4(*(const float4*)(opw + i4)); return; }
  i4 -= CA_N1;
  if (i4 < CA_N2){ *(ushort4*)(inpwb + i4) = cvt4(*(const float4*)(inpw + i4)); return; }
  i4 -= CA_N2;
  if (i4 < CA_N3){
    const long long l = i4 / (128*1536), rem = i4 % (128*1536);
    const long long r = rem / 1536, k = rem % 1536;
    ushort4 o;
    if (r < 80) o = cvt4(*(const float4*)(xpw + (l*80 + r)*1536 + k));
    else { o.x=0;o.y=0;o.z=0;o.w=0; }
    *(ushort4*)(xpwb + i4) = o; return;
  }
  i4 -= CA_N3;
  if (i4 < CA_N4){
    const long long l = i4 / (1536*64), rem = i4 % (1536*64);
    const long long r = rem / 64, c = rem % 64;
    ushort4 o;
    if (c < 48) o = cvt4(*(const float4*)(dtw + (l*1536 + r)*48 + c));
    else { o.x=0;o.y=0;o.z=0;o.w=0; }
    *(ushort4*)(dtwb + i4) = o;
  }
}

// ---------------- transpose: x (B,256,512) -> xtb (B,512,256) bf16 ----------------
__global__ void transpose_x(const float* __restrict__ x, unsigned short* __restrict__ xtb){
  __shared__ float s[32][33];
  int b = blockIdx.z;
  int t0 = blockIdx.x*32, c0 = blockIdx.y*32;
  int tx = threadIdx.x, ty = threadIdx.y;
  s[ty][tx] = x[((size_t)b*256 + (c0+ty))*512 + (t0+tx)];
  __syncthreads();
  xtb[((size_t)b*512 + (t0+ty))*256 + (c0+tx)] = f2bf(s[tx][ty]);
}

// ---------------- bf16 MFMA GEMM w/ global_load_lds staging ----------------
// C[M,N] = A[M,K] * W[N,K]^T (+bias). M%128==0, N%128==0, K%32==0. 256 thr = 4 waves.
// LDS unpadded 128x32 tiles; k-chunk swizzle: LDS(row,khp) holds khl=(khp-(row>>1))&3.
__global__ __launch_bounds__(256) void gemm_bf16(
    const unsigned short* __restrict__ A, const unsigned short* __restrict__ Wb,
    const float* __restrict__ bias,
    float* __restrict__ C, int M, int N, int K)
{
  __shared__ unsigned short As[128*32];
  __shared__ unsigned short Ws[128*32];
  const int tid = threadIdx.x;
  const int bm = blockIdx.y*128, bn = blockIdx.x*128;
  const int wave = tid >> 6, lane = tid & 63;
  const int wm = (wave >> 1)*64, wn = (wave & 1)*64;
  const int fr = lane & 15, quad = lane >> 4;
  f32x4 acc[4][4] = {};
  const int row0 = (wave*64 + lane) >> 2;
  const int khp  = lane & 3;
  const int khl  = (khp + 4 - ((row0 >> 1) & 3)) & 3;
  const unsigned short* Ag = A  + (size_t)(bm + row0)*K + khl*8;
  const unsigned short* Wg = Wb + (size_t)(bn + row0)*K + khl*8;
  const size_t rstep = (size_t)64*K;
  unsigned short* ldsA = As + wave*512;
  unsigned short* ldsW = Ws + wave*512;

  for (int k0 = 0; k0 < K; k0 += 32){
    GLL(Ag + k0,          ldsA);
    GLL(Ag + rstep + k0,  ldsA + 2048);
    GLL(Wg + k0,          ldsW);
    GLL(Wg + rstep + k0,  ldsW + 2048);
    __syncthreads();
    bf16x8 a[4], b[4];
    #pragma unroll
    for (int i=0;i<4;i++){
      const int row = wm + i*16 + fr;
      a[i] = *(const bf16x8*)(As + row*32 + (((quad + (row>>1)) & 3)*8));
    }
    #pragma unroll
    for (int j=0;j<4;j++){
      const int row = wn + j*16 + fr;
      b[j] = *(const bf16x8*)(Ws + row*32 + (((quad + (row>>1)) & 3)*8));
    }
    #pragma unroll
    for (int i=0;i<4;i++)
      #pragma unroll
      for (int j=0;j<4;j++)
        acc[i][j] = __builtin_amdgcn_mfma_f32_16x16x32_bf16(a[i], b[j], acc[i][j], 0, 0, 0);
    __syncthreads();
  }
  #pragma unroll
  for (int i=0;i<4;i++){
    #pragma unroll
    for (int r=0;r<4;r++){
      const int row = bm + wm + i*16 + quad*4 + r;
      float* Cp = C + (size_t)row*N + bn + wn + fr;
      #pragma unroll
      for (int j=0;j<4;j++){
        const int col = bn + wn + j*16 + fr;
        Cp[j*16] = acc[i][j][r] + (bias ? bias[col] : 0.f);
      }
    }
  }
}

// ---------------- bf16 MFMA GEMM, split-K (out_proj partials) ----------------
__global__ __launch_bounds__(256) void gemm_bf16_sk(
    const unsigned short* __restrict__ A, const unsigned short* __restrict__ Wb,
    float* __restrict__ P0, float* __restrict__ P1, int M, int N, int K)
{
  __shared__ unsigned short As[128*32];
  __shared__ unsigned short Ws[128*32];
  const int tid = threadIdx.x;
  const int bm = blockIdx.y*128, bn = blockIdx.x*128;
  const int s = blockIdx.z;
  const int koff = s*OKC;
  const int wave = tid >> 6, lane = tid & 63;
  const int wm = (wave >> 1)*64, wn = (wave & 1)*64;
  const int fr = lane & 15, quad = lane >> 4;
  f32x4 acc[4][4] = {};
  const int row0 = (wave*64 + lane) >> 2;
  const int khp  = lane & 3;
  const int khl  = (khp + 4 - ((row0 >> 1) & 3)) & 3;
  const unsigned short* Ag = A  + (size_t)(bm + row0)*K + koff + khl*8;
  const unsigned short* Wg = Wb + (size_t)(bn + row0)*K + koff + khl*8;
  const size_t rstep = (size_t)64*K;
  unsigned short* ldsA = As + wave*512;
  unsigned short* ldsW = Ws + wave*512;

  for (int k0 = 0; k0 < OKC; k0 += 32){
    GLL(Ag + k0,          ldsA);
    GLL(Ag + rstep + k0,  ldsA + 2048);
    GLL(Wg + k0,          ldsW);
    GLL(Wg + rstep + k0,  ldsW + 2048);
    __syncthreads();
    bf16x8 a[4], b[4];
    #pragma unroll
    for (int i=0;i<4;i++){
      const int row = wm + i*16 + fr;
      a[i] = *(const bf16x8*)(As + row*32 + (((quad + (row>>1)) & 3)*8));
    }
    #pragma unroll
    for (int j=0;j<4;j++){
      const int row = wn + j*16 + fr;
      b[j] = *(const bf16x8*)(Ws + row*32 + (((quad + (row>>1)) & 3)*8));
    }
    #pragma unroll
    for (int i=0;i<4;i++)
      #pragma unroll
      for (int j=0;j<4;j++)
        acc[i][j] = __builtin_amdgcn_mfma_f32_16x16x32_bf16(a[i], b[j], acc[i][j], 0, 0, 0);
    __syncthreads();
  }
  float* Cb = (s < 2 ? P0 : P1) + (size_t)(s & 1)*MN_OUT;
  #pragma unroll
  for (int i=0;i<4;i++){
    #pragma unroll
    for (int r=0;r<4;r++){
      const int row = bm + wm + i*16 + quad*4 + r;
      float* Cp = Cb + (size_t)row*N + bn + wn + fr;
      #pragma unroll
      for (int j=0;j<4;j++)
        Cp[j*16] = acc[i][j][r];
    }
  }
}

// ---------------- x_proj bf16 split-K: partials (s,row,80) ----------------
// A = ubf (2048x1536), W = xpwb (128x1536 zero-padded rows 80..127). grid (16, XS).
__global__ __launch_bounds__(256) void gemm_bf16_xp(
    const unsigned short* __restrict__ A, const unsigned short* __restrict__ Wb,
    float* __restrict__ part)
{
  __shared__ unsigned short As[128*32];
  __shared__ unsigned short Ws[128*32];
  const int tid = threadIdx.x;
  const int bm = blockIdx.x*128;
  const int s = blockIdx.y;
  const int koff = s*XKC;
  const int wave = tid >> 6, lane = tid & 63;
  const int wm = (wave >> 1)*64, wn = (wave & 1)*64;
  const int fr = lane & 15, quad = lane >> 4;
  f32x4 acc[4][4] = {};
  const int row0 = (wave*64 + lane) >> 2;
  const int khp  = lane & 3;
  const int khl  = (khp + 4 - ((row0 >> 1) & 3)) & 3;
  const unsigned short* Ag = A  + (size_t)(bm + row0)*D_INNER + koff + khl*8;
  const unsigned short* Wg = Wb + (size_t)row0*D_INNER + koff + khl*8;
  const size_t rstep = (size_t)64*D_INNER;
  unsigned short* ldsA = As + wave*512;
  unsigned short* ldsW = Ws + wave*512;

  for (int k0 = 0; k0 < XKC; k0 += 32){
    GLL(Ag + k0,          ldsA);
    GLL(Ag + rstep + k0,  ldsA + 2048);
    GLL(Wg + k0,          ldsW);
    GLL(Wg + rstep + k0,  ldsW + 2048);
    __syncthreads();
    bf16x8 a[4], b[4];
    #pragma unroll
    for (int i=0;i<4;i++){
      const int row = wm + i*16 + fr;
      a[i] = *(const bf16x8*)(As + row*32 + (((quad + (row>>1)) & 3)*8));
    }
    #pragma unroll
    for (int j=0;j<4;j++){
      const int row = wn + j*16 + fr;
      b[j] = *(const bf16x8*)(Ws + row*32 + (((quad + (row>>1)) & 3)*8));
    }
    #pragma unroll
    for (int i=0;i<4;i++)
      #pragma unroll
      for (int j=0;j<4;j++)
        acc[i][j] = __builtin_amdgcn_mfma_f32_16x16x32_bf16(a[i], b[j], acc[i][j], 0, 0, 0);
    __syncthreads();
  }
  #pragma unroll
  for (int i=0;i<4;i++){
    #pragma unroll
    for (int r=0;r<4;r++){
      const int row = bm + wm + i*16 + quad*4 + r;
      #pragma unroll
      for (int j=0;j<4;j++){
        const int col = wn + j*16 + fr;
        if (col < XP_N)
          part[((size_t)s*ROWS + row)*XP_N + col] = acc[i][j][r];
      }
    }
  }
}

// reduce 8 partials -> xp fp32 (80 cols) + xpb bf16 (64-col padded, cols 48..63 = 0)
__global__ __launch_bounds__(256) void reduce_xp(const float* __restrict__ part,
                                                 float* __restrict__ xp,
                                                 unsigned short* __restrict__ xpb){
  const int i = blockIdx.x*256 + threadIdx.x;
  if (i >= ROWS*XP_N) return;
  const int row = i / XP_N, c = i % XP_N;
  float s = 0.f;
  #pragma unroll
  for (int k=0;k<XS;k++) s += part[(size_t)k*ROWS*XP_N + i];
  xp[i] = s;
  if (c < 48) xpb[row*64 + c] = f2bf(s);
  else if (c < 64) xpb[row*64 + c] = 0;
}

// ---------------- dt_proj bf16 (K=64 padded) + bias + softplus -> delta fp32 ----------------
// A = xpb (2048x64), W = dtwb (1536x64). grid (12,16).
__global__ __launch_bounds__(256) void gemm_bf16_dt(
    const unsigned short* __restrict__ A, const unsigned short* __restrict__ Wb,
    const float* __restrict__ bias, float* __restrict__ C)
{
  __shared__ unsigned short As[128*32];
  __shared__ unsigned short Ws[128*32];
  const int tid = threadIdx.x;
  const int bm = blockIdx.y*128, bn = blockIdx.x*128;
  const int wave = tid >> 6, lane = tid & 63;
  const int wm = (wave >> 1)*64, wn = (wave & 1)*64;
  const int fr = lane & 15, quad = lane >> 4;
  f32x4 acc[4][4] = {};
  const int row0 = (wave*64 + lane) >> 2;
  const int khp  = lane & 3;
  const int khl  = (khp + 4 - ((row0 >> 1) & 3)) & 3;
  const unsigned short* Ag = A  + (size_t)(bm + row0)*64 + khl*8;
  const unsigned short* Wg = Wb + (size_t)(bn + row0)*64 + khl*8;
  const size_t rstepA = (size_t)64*64;
  unsigned short* ldsA = As + wave*512;
  unsigned short* ldsW = Ws + wave*512;

  for (int k0 = 0; k0 < 64; k0 += 32){
    GLL(Ag + k0,           ldsA);
    GLL(Ag + rstepA + k0,  ldsA + 2048);
    GLL(Wg + k0,           ldsW);
    GLL(Wg + rstepA + k0,  ldsW + 2048);
    __syncthreads();
    bf16x8 a[4], b[4];
    #pragma unroll
    for (int i=0;i<4;i++){
      const int row = wm + i*16 + fr;
      a[i] = *(const bf16x8*)(As + row*32 + (((quad + (row>>1)) & 3)*8));
    }
    #pragma unroll
    for (int j=0;j<4;j++){
      const int row = wn + j*16 + fr;
      b[j] = *(const bf16x8*)(Ws + row*32 + (((quad + (row>>1)) & 3)*8));
    }
    #pragma unroll
    for (int i=0;i<4;i++)
      #pragma unroll
      for (int j=0;j<4;j++)
        acc[i][j] = __builtin_amdgcn_mfma_f32_16x16x32_bf16(a[i], b[j], acc[i][j], 0, 0, 0);
    __syncthreads();
  }
  #pragma unroll
  for (int i=0;i<4;i++){
    #pragma unroll
    for (int r=0;r<4;r++){
      const int row = bm + wm + i*16 + quad*4 + r;
      float* Cp = C + (size_t)row*D_INNER + bn + wn + fr;
      #pragma unroll
      for (int j=0;j<4;j++){
        const int col = bn + wn + j*16 + fr;
        float v = acc[i][j][r] + bias[col];
        v = (v > 20.f) ? v : log1pf(__expf(v));
        Cp[j*16] = v;
      }
    }
  }
}

// ---------------- fused: [out_proj partial-reduce +] residual add + RMSNorm ----------------
__global__ __launch_bounds__(256) void fused_norm(
    float* __restrict__ resid, const float* __restrict__ P0, const float* __restrict__ P1,
    const float* __restrict__ w, unsigned short* __restrict__ obf, float* __restrict__ ofp)
{
  const int row = blockIdx.x;
  const int tid = threadIdx.x;
  float v[3];
  float ss = 0.f;
  #pragma unroll
  for (int i=0;i<3;i++){
    const int c = tid + i*256;
    const size_t idx = (size_t)row*768 + c;
    float r = resid[idx];
    if (P0) r += (P0[idx] + P0[MN_OUT + idx]) + (P1[idx] + P1[MN_OUT + idx]);
    v[i] = r;
    ss += r*r;
  }
  #pragma unroll
  for (int off=32; off>=1; off>>=1) ss += __shfl_xor(ss, off);
  __shared__ float sred[4];
  const int lane = tid & 63, wv = tid >> 6;
  if (lane == 0) sred[wv] = ss;
  __syncthreads();
  const float tot = sred[0]+sred[1]+sred[2]+sred[3];
  const float scale = rsqrtf(tot*(1.0f/768.0f) + 1e-5f);
  #pragma unroll
  for (int i=0;i<3;i++){
    const int c = tid + i*256;
    const size_t idx = (size_t)row*768 + c;
    if (P0) resid[idx] = v[i];
    const float o = v[i]*scale*w[c];
    if (obf) obf[idx] = f2bf(o);
    else     ofp[idx] = o;
  }
}

// ---------------- causal depthwise conv (K=4) + silu -> ucv fp32 + ubf bf16 ----------------
__global__ __launch_bounds__(256) void conv_silu(
    const float* __restrict__ xz, const float* __restrict__ cw,
    const float* __restrict__ cb, float* __restrict__ uo,
    unsigned short* __restrict__ ub)
{
  const int idx = blockIdx.x*256 + threadIdx.x;
  if (idx >= ROWS*D_INNER) return;
  const int d = idx % D_INNER;
  const int row = idx / D_INNER;
  const int t = row & (T_SZ-1);
  float acc = cb[d];
  #pragma unroll
  for (int k=0;k<4;k++){
    const int tt = t - 3 + k;
    if (tt >= 0)
      acc += xz[(size_t)(row - 3 + k)*3072 + d] * cw[d*4 + k];
  }
  const float s = siluf_(acc);
  uo[idx] = s;
  ub[idx] = f2bf(s);
}

// ---------------- chunked selective scan: lane = (b,c,d), 16 n-states in regs ----------------
__global__ __launch_bounds__(256) void scan_pass1(
    const float* __restrict__ delta, const float* __restrict__ u,
    const float* __restrict__ xp, const float* __restrict__ alog,
    float* __restrict__ Pend, float* __restrict__ Hend)
{
  const int d = blockIdx.x*256 + threadIdx.x;
  const int b = blockIdx.y, c = blockIdx.z;
  float4 t0 = *(const float4*)(alog + d*16 + 0);
  float4 t1 = *(const float4*)(alog + d*16 + 4);
  float4 t2 = *(const float4*)(alog + d*16 + 8);
  float4 t3 = *(const float4*)(alog + d*16 + 12);
  float Av[16] = {t0.x,t0.y,t0.z,t0.w,t1.x,t1.y,t1.z,t1.w,
                  t2.x,t2.y,t2.z,t2.w,t3.x,t3.y,t3.z,t3.w};
  float h[16], P[16];
  #pragma unroll
  for (int n=0;n<16;n++){ Av[n] = -__expf(Av[n]); h[n]=0.f; P[n]=1.f; }
  const size_t row0 = (size_t)b*T_SZ + (size_t)c*CT;
  const float* dp = delta + row0*D_INNER + d;
  const float* up = u     + row0*D_INNER + d;
  const float* bp = xp    + row0*XP_N + 48;
  for (int t=0;t<CT;t++){
    const float dv = dp[(size_t)t*D_INNER];
    const float uv = up[(size_t)t*D_INNER];
    const float4 B0 = *(const float4*)(bp + (size_t)t*XP_N);
    const float4 B1 = *(const float4*)(bp + (size_t)t*XP_N + 4);
    const float4 B2 = *(const float4*)(bp + (size_t)t*XP_N + 8);
    const float4 B3 = *(const float4*)(bp + (size_t)t*XP_N + 12);
    const float Bv[16] = {B0.x,B0.y,B0.z,B0.w,B1.x,B1.y,B1.z,B1.w,
                          B2.x,B2.y,B2.z,B2.w,B3.x,B3.y,B3.z,B3.w};
    const float du = dv*uv;
    #pragma unroll
    for (int n=0;n<16;n++){
      const float dA = __expf(dv*Av[n]);
      P[n] *= dA;
      h[n] = dA*h[n] + du*Bv[n];
    }
  }
  float* Pp = Pend + ((size_t)(b*CH+c)*D_INNER + d)*16;
  float* Hp = Hend + ((size_t)(b*CH+c)*D_INNER + d)*16;
  *(float4*)(Pp+ 0) = make_float4(P[0],P[1],P[2],P[3]);
  *(float4*)(Pp+ 4) = make_float4(P[4],P[5],P[6],P[7]);
  *(float4*)(Pp+ 8) = make_float4(P[8],P[9],P[10],P[11]);
  *(float4*)(Pp+12) = make_float4(P[12],P[13],P[14],P[15]);
  *(float4*)(Hp+ 0) = make_float4(h[0],h[1],h[2],h[3]);
  *(float4*)(Hp+ 4) = make_float4(h[4],h[5],h[6],h[7]);
  *(float4*)(Hp+ 8) = make_float4(h[8],h[9],h[10],h[11]);
  *(float4*)(Hp+12) = make_float4(h[12],h[13],h[14],h[15]);
}

// Pass 3 w/ inline prefix combine over Pend/Hend (chunks < c), then emit y bf16.
__global__ __launch_bounds__(256) void scan_pass3(
    const float* __restrict__ delta, const float* __restrict__ u,
    const float* __restrict__ xp, const float* __restrict__ xz,
    const float* __restrict__ alog, const float* __restrict__ Dp,
    const float* __restrict__ Pend, const float* __restrict__ Hend,
    unsigned short* __restrict__ yb)
{
  const int d = blockIdx.x*256 + threadIdx.x;
  const int b = blockIdx.y, c = blockIdx.z;
  float4 t0 = *(const float4*)(alog + d*16 + 0);
  float4 t1 = *(const float4*)(alog + d*16 + 4);
  float4 t2 = *(const float4*)(alog + d*16 + 8);
  float4 t3 = *(const float4*)(alog + d*16 + 12);
  float Av[16] = {t0.x,t0.y,t0.z,t0.w,t1.x,t1.y,t1.z,t1.w,
                  t2.x,t2.y,t2.z,t2.w,t3.x,t3.y,t3.z,t3.w};
  float h[16];
  #pragma unroll
  for (int n=0;n<16;n++){ Av[n] = -__expf(Av[n]); h[n] = 0.f; }
  // prefix combine: h = P[cc]*h + H[cc], cc = 0..c-1
  for (int cc=0; cc<c; cc++){
    const float* Pp = Pend + ((size_t)(b*CH+cc)*D_INNER + d)*16;
    const float* Hp = Hend + ((size_t)(b*CH+cc)*D_INNER + d)*16;
    float4 p0 = *(const float4*)(Pp+0),  p1 = *(const float4*)(Pp+4);
    float4 p2 = *(const float4*)(Pp+8),  p3 = *(const float4*)(Pp+12);
    float4 q0 = *(const float4*)(Hp+0),  q1 = *(const float4*)(Hp+4);
    float4 q2 = *(const float4*)(Hp+8),  q3 = *(const float4*)(Hp+12);
    const float Pv[16] = {p0.x,p0.y,p0.z,p0.w,p1.x,p1.y,p1.z,p1.w,
                          p2.x,p2.y,p2.z,p2.w,p3.x,p3.y,p3.z,p3.w};
    const float Hv[16] = {q0.x,q0.y,q0.z,q0.w,q1.x,q1.y,q1.z,q1.w,
                          q2.x,q2.y,q2.z,q2.w,q3.x,q3.y,q3.z,q3.w};
    #pragma unroll
    for (int n=0;n<16;n++) h[n] = Pv[n]*h[n] + Hv[n];
  }
  const float Dv = Dp[d];
  const size_t row0 = (size_t)b*T_SZ + (size_t)c*CT;
  const float* dp = delta + row0*D_INNER + d;
  const float* up = u     + row0*D_INNER + d;
  const float* bp = xp    + row0*XP_N + 48;
  const float* cp = xp    + row0*XP_N + 64;
  const float* zp = xz    + row0*3072 + 1536 + d;
  unsigned short* yp = yb + row0*D_INNER + d;
  for (int t=0;t<CT;t++){
    const float dv = dp[(size_t)t*D_INNER];
    const float uv = up[(size_t)t*D_INNER];
    const float zv = zp[(size_t)t*3072];
    const float4 B0 = *(const float4*)(bp + (size_t)t*XP_N);
    const float4 B1 = *(const float4*)(bp + (size_t)t*XP_N + 4);
    const float4 B2 = *(const float4*)(bp + (size_t)t*XP_N + 8);
    const float4 B3 = *(const float4*)(bp + (size_t)t*XP_N + 12);
    const float4 C0 = *(const float4*)(cp + (size_t)t*XP_N);
    const float4 C1 = *(const float4*)(cp + (size_t)t*XP_N + 4);
    const float4 C2 = *(const float4*)(cp + (size_t)t*XP_N + 8);
    const float4 C3 = *(const float4*)(cp + (size_t)t*XP_N + 12);
    const float Bv[16] = {B0.x,B0.y,B0.z,B0.w,B1.x,B1.y,B1.z,B1.w,
                          B2.x,B2.y,B2.z,B2.w,B3.x,B3.y,B3.z,B3.w};
    const float Cv[16] = {C0.x,C0.y,C0.z,C0.w,C1.x,C1.y,C1.z,C1.w,
                          C2.x,C2.y,C2.z,C2.w,C3.x,C3.y,C3.z,C3.w};
    const float du = dv*uv;
    float p = 0.f;
    #pragma unroll
    for (int n=0;n<16;n++){
      const float dA = __expf(dv*Av[n]);
      h[n] = dA*h[n] + du*Bv[n];
      p += h[n]*Cv[n];
    }
    yp[(size_t)t*D_INNER] = f2bf((p + uv*Dv)*siluf_(zv));
  }
}

// ---------------- mean pool stage 1 ----------------
__global__ __launch_bounds__(256) void pool_partial(const float* __restrict__ normed,
                                                    float* __restrict__ part){
  const int i = blockIdx.x*256 + threadIdx.x;
  const int s = blockIdx.y;
  const int b = i / 768, m = i % 768;
  float sum = 0.f;
  const float* p = normed + ((size_t)b*T_SZ + s*32)*768 + m;
  #pragma unroll
  for (int t=0; t<32; t++) sum += p[(size_t)t*768];
  part[s*3072 + i] = sum;
}

// ---------------- fused pool-final + classifier: out (4,10) ----------------
__global__ __launch_bounds__(256) void pool_cls(const float* __restrict__ part,
                                                const float* __restrict__ cw,
                                                const float* __restrict__ cb,
                                                float* __restrict__ out){
  __shared__ float ls[768];
  const int b = blockIdx.x;
  const int tid = threadIdx.x;
  #pragma unroll
  for (int i=0;i<3;i++){
    const int m = tid + i*256;
    float s = 0.f;
    #pragma unroll
    for (int c=0;c<16;c++) s += part[c*3072 + b*768 + m];
    ls[m] = s * (1.0f/T_SZ);
  }
  __syncthreads();
  const int wave = tid >> 6, lane = tid & 63;
  for (int o = wave; o < 10; o += 4){
    float s = 0.f;
    for (int k = lane; k < 768; k += 64) s += ls[k]*cw[o*768 + k];
    #pragma unroll
    for (int off=32; off>=1; off>>=1) s += __shfl_xor(s, off);
    if (lane == 0) out[b*10 + o] = s + cb[o];
  }
}

extern "C" void kernel_launch(void* const* d_in, const int* in_sizes, int n_in,
                              void* d_out, int out_size, void* d_ws, size_t ws_size,
                              hipStream_t stream) {
  const float* x         = (const float*)d_in[0];
  const float* in_proj_w = (const float*)d_in[1];
  const float* conv_w    = (const float*)d_in[2];
  const float* conv_b    = (const float*)d_in[3];
  const float* x_proj_w  = (const float*)d_in[4];
  const float* dt_proj_w = (const float*)d_in[5];
  const float* dt_proj_b = (const float*)d_in[6];
  const float* A_log     = (const float*)d_in[7];
  const float* D_param   = (const float*)d_in[8];
  const float* out_proj_w= (const float*)d_in[9];
  const float* norm_w    = (const float*)d_in[10];
  const float* norm_f_w  = (const float*)d_in[11];
  const float* inp_w     = (const float*)d_in[12];
  const float* inp_b     = (const float*)d_in[13];
  const float* cls_w     = (const float*)d_in[14];
  const float* cls_b     = (const float*)d_in[15];
  float* out = (float*)d_out;

  char* ws = (char*)d_ws;
  auto carve = [&](size_t nelem)->float* {
    float* p = (float*)ws;
    ws += ((nelem*sizeof(float) + 255)/256)*256;
    return p;
  };
  float* xtb_f  = carve((size_t)ROWS*256/2);       // bf16 transposed input
  float* resid  = carve((size_t)ROWS*768);
  float* normed = carve((size_t)ROWS*768);         // bf16 normed (lower) / Pend during scan / fp32 final
  float* hidden = carve((size_t)ROWS*768);         // Hend during scan
  float* xz     = carve((size_t)ROWS*3072);
  float* ucv    = carve((size_t)ROWS*1536);        // out_proj partials s=2,3 after scan
  float* xp     = carve((size_t)ROWS*XP_N);
  float* delta  = carve((size_t)ROWS*1536);        // out_proj partials s=0,1 after scan
  float* ybf_f  = carve((size_t)ROWS*1536/2);      // bf16 y
  float* ubf_f  = carve((size_t)ROWS*1536/2);      // bf16 u
  float* xpb_f  = carve((size_t)ROWS*64/2);        // bf16 xp (dt cols, padded 64)
  float* wbi_f  = carve((size_t)CA_N0/2);          // all-layer bf16 in_proj
  float* wbo_f  = carve((size_t)CA_N1/2);          // all-layer bf16 out_proj
  float* wip_f  = carve((size_t)CA_N2/2);          // bf16 inp_w
  float* wxp_f  = carve((size_t)CA_N3/2);          // all-layer bf16 x_proj (padded 128)
  float* wdt_f  = carve((size_t)CA_N4/2);          // all-layer bf16 dt_proj (padded 64)
  float* xpart  = carve((size_t)XS*ROWS*XP_N);
  float* ppool  = carve((size_t)16*3072);

  unsigned short* xtb = (unsigned short*)xtb_f;
  unsigned short* normedb = (unsigned short*)normed;
  unsigned short* ybf = (unsigned short*)ybf_f;
  unsigned short* ubf = (unsigned short*)ubf_f;
  unsigned short* xpb = (unsigned short*)xpb_f;
  unsigned short* wbi = (unsigned short*)wbi_f;
  unsigned short* wbo = (unsigned short*)wbo_f;
  unsigned short* wip = (unsigned short*)wip_f;
  unsigned short* wxp = (unsigned short*)wxp_f;
  unsigned short* wdt = (unsigned short*)wdt_f;
  float* Pend = normed;    // dead during scan
  float* Hend = hidden;    // dead during scan

  cast_all<<<15168, 256, 0, stream>>>(in_proj_w, wbi, out_proj_w, wbo,
                                      inp_w, wip, x_proj_w, wxp, dt_proj_w, wdt);
  transpose_x<<<dim3(16,8,4), dim3(32,32), 0, stream>>>(x, xtb);
  gemm_bf16<<<dim3(6,16), 256, 0, stream>>>(xtb, wip, inp_b, resid, ROWS, 768, 256);

  for (int l = 0; l < 4; l++){
    fused_norm<<<2048, 256, 0, stream>>>(resid, l ? delta : nullptr, l ? ucv : nullptr,
                                         norm_w + (size_t)l*768, normedb, nullptr);
    gemm_bf16<<<dim3(24,16), 256, 0, stream>>>(normedb, wbi + (size_t)l*3072*768, nullptr,
                                               xz, ROWS, 3072, 768);
    conv_silu<<<(ROWS*D_INNER)/256, 256, 0, stream>>>(xz, conv_w + (size_t)l*1536*4,
                                                      conv_b + (size_t)l*1536, ucv, ubf);
    gemm_bf16_xp<<<dim3(16,XS), 256, 0, stream>>>(ubf, wxp + (size_t)l*128*1536, xpart);
    reduce_xp<<<(ROWS*XP_N)/256, 256, 0, stream>>>(xpart, xp, xpb);
    gemm_bf16_dt<<<dim3(12,16), 256, 0, stream>>>(xpb, wdt + (size_t)l*1536*64,
                                                  dt_proj_b + (size_t)l*1536, delta);
    scan_pass1<<<dim3(6,B_SZ,CH-1), 256, 0, stream>>>(delta, ucv, xp,
                                               A_log + (size_t)l*1536*16, Pend, Hend);
    scan_pass3<<<dim3(6,B_SZ,CH), 256, 0, stream>>>(delta, ucv, xp, xz,
                                               A_log + (size_t)l*1536*16, D_param + (size_t)l*1536,
                                               Pend, Hend, ybf);
    gemm_bf16_sk<<<dim3(6,16,OS), 256, 0, stream>>>(ybf, wbo + (size_t)l*768*1536,
                                                    delta, ucv, ROWS, 768, 1536);
  }

  fused_norm<<<2048, 256, 0, stream>>>(resid, delta, ucv, norm_f_w, nullptr, normed);
  pool_partial<<<dim3(12,16), 256, 0, stream>>>(normed, ppool);
  pool_cls<<<4, 256, 0, stream>>>(ppool, cls_w, cls_b, out);
}